// Round 11
// baseline (741.233 us; speedup 1.0000x reference)
//
#include <hip/hip_runtime.h>
#include <math.h>
#include <stdint.h>

#define NPOS  32768
#define LOG2N 15
#define BATCH 8
#define TOTAL (BATCH * NPOS)   // 262144 positions
#define HE    ((size_t)16 * TOTAL)   // one h buffer, elements (16 MiB)

typedef __attribute__((ext_vector_type(8))) short short8v;  // 8 bf16 = 4 VGPR
typedef __attribute__((ext_vector_type(4))) float f32x4;    // MFMA C/D

__device__ __forceinline__ float fast_tanh(float x) {
    float t = __expf(-2.f * x);
    return fmaf(2.f, __builtin_amdgcn_rcpf(1.f + t), -1.f);
}
__device__ __forceinline__ float fast_sigmoid(float x) {
    return __builtin_amdgcn_rcpf(1.f + __expf(-x));
}
__device__ __forceinline__ unsigned short bf16rne(float x) {
    unsigned u = __float_as_uint(x);
    u = (u + 0x7fffu + ((u >> 16) & 1u)) >> 16;
    return (unsigned short)u;
}

// ======================================================================
// Defer-skip path. Layout: H_i = [pos][16] fp32 (64B per position).
// ======================================================================

__global__ __launch_bounds__(256) void init_kernel_rm(
    const int* __restrict__ x_int, const float* __restrict__ W0,
    const float* __restrict__ b0, float* __restrict__ h)
{
    int t0 = (blockIdx.x * 256 + threadIdx.x) * 2;
    int n0 = t0 & (NPOS - 1);
    const float sc = 1.f / 32768.f;
    float xs0  = (n0 >= 1) ? (float)x_int[t0 - 1] * sc : 0.f;
    float xs1  = (float)x_int[t0] * sc;
    float xsp0 = (n0 >= 2) ? (float)x_int[t0 - 2] * sc : 0.f;
    float xsp1 = xs0;

    float wa[16], wb[16];
#pragma unroll
    for (int c = 0; c < 16; ++c) {
        wa[c] = xs0 + W0[c * 2 + 0] * xsp0 + W0[c * 2 + 1] * xs0 + b0[c];
        wb[c] = xs1 + W0[c * 2 + 0] * xsp1 + W0[c * 2 + 1] * xs1 + b0[c];
    }
    float4* o = (float4*)(h + (size_t)t0 * 16);
#pragma unroll
    for (int q = 0; q < 4; ++q)
        o[q] = make_float4(wa[4 * q], wa[4 * q + 1], wa[4 * q + 2], wa[4 * q + 3]);
#pragma unroll
    for (int q = 0; q < 4; ++q)
        o[4 + q] = make_float4(wb[4 * q], wb[4 * q + 1], wb[4 * q + 2], wb[4 * q + 3]);
}

// ---- residual layer, no skip, position-major rows -----------------------
__global__ __launch_bounds__(256, 2) void layer_kernel_rm(
    const float* __restrict__ hIn, float* __restrict__ hOut,
    const float* __restrict__ wf, const float* __restrict__ bfv,
    const float* __restrict__ wg, const float* __restrict__ bgv,
    int d)
{
    int t0 = (blockIdx.x * 256 + threadIdx.x) * 2;
    int n0 = t0 & (NPOS - 1);

    // current rows t0, t0+1  (128B contiguous)
    float ra[16], rb[16];
    {
        const float4* p = (const float4*)(hIn + (size_t)t0 * 16);
#pragma unroll
        for (int q = 0; q < 4; ++q) {
            float4 v = p[q];
            ra[4 * q] = v.x; ra[4 * q + 1] = v.y; ra[4 * q + 2] = v.z; ra[4 * q + 3] = v.w;
        }
#pragma unroll
        for (int q = 0; q < 4; ++q) {
            float4 v = p[4 + q];
            rb[4 * q] = v.x; rb[4 * q + 1] = v.y; rb[4 * q + 2] = v.z; rb[4 * q + 3] = v.w;
        }
    }

    // previous rows (dilated)
    float pa[16], pb[16];
    if (d == 1) {
        bool v = (n0 >= 1);
        const float4* p = (const float4*)(hIn + (size_t)(v ? (t0 - 1) : t0) * 16);
#pragma unroll
        for (int q = 0; q < 4; ++q) {
            float4 x = p[q];
            pa[4 * q] = v ? x.x : 0.f; pa[4 * q + 1] = v ? x.y : 0.f;
            pa[4 * q + 2] = v ? x.z : 0.f; pa[4 * q + 3] = v ? x.w : 0.f;
        }
#pragma unroll
        for (int c = 0; c < 16; ++c) pb[c] = ra[c];
    } else {
        bool v = (n0 >= d);
        const float4* p = (const float4*)(hIn + (size_t)(v ? (t0 - d) : t0) * 16);
#pragma unroll
        for (int q = 0; q < 4; ++q) {
            float4 x = p[q];
            pa[4 * q] = v ? x.x : 0.f; pa[4 * q + 1] = v ? x.y : 0.f;
            pa[4 * q + 2] = v ? x.z : 0.f; pa[4 * q + 3] = v ? x.w : 0.f;
        }
#pragma unroll
        for (int q = 0; q < 4; ++q) {
            float4 x = p[4 + q];
            pb[4 * q] = v ? x.x : 0.f; pb[4 * q + 1] = v ? x.y : 0.f;
            pb[4 * q + 2] = v ? x.z : 0.f; pb[4 * q + 3] = v ? x.w : 0.f;
        }
    }

    float wa[16], wb[16];
#pragma unroll
    for (int c = 0; c < 16; ++c) {
        float fax = bfv[c], fay = bfv[c];
        float gax = bgv[c], gay = bgv[c];
#pragma unroll
        for (int ic = 0; ic < 16; ++ic) {
            float wf0 = wf[(c * 16 + ic) * 2 + 0];
            float wf1 = wf[(c * 16 + ic) * 2 + 1];
            float wg0 = wg[(c * 16 + ic) * 2 + 0];
            float wg1 = wg[(c * 16 + ic) * 2 + 1];
            fax = fmaf(wf0, pa[ic], fax); fax = fmaf(wf1, ra[ic], fax);
            fay = fmaf(wf0, pb[ic], fay); fay = fmaf(wf1, rb[ic], fay);
            gax = fmaf(wg0, pa[ic], gax); gax = fmaf(wg1, ra[ic], gax);
            gay = fmaf(wg0, pb[ic], gay); gay = fmaf(wg1, rb[ic], gay);
        }
        wa[c] = fmaf(fast_tanh(fax), fast_sigmoid(gax), ra[c]);
        wb[c] = fmaf(fast_tanh(fay), fast_sigmoid(gay), rb[c]);
    }

    float4* o = (float4*)(hOut + (size_t)t0 * 16);
#pragma unroll
    for (int q = 0; q < 4; ++q)
        o[q] = make_float4(wa[4 * q], wa[4 * q + 1], wa[4 * q + 2], wa[4 * q + 3]);
#pragma unroll
    for (int q = 0; q < 4; ++q)
        o[4 + q] = make_float4(wb[4 * q], wb[4 * q + 1], wb[4 * q + 2], wb[4 * q + 3]);
}

// ---- final: MFMA skip-sum + agg + MFMA logits (row-major H) -------------
__global__ __launch_bounds__(256, 2) void final_kernel_ds3(
    const float* __restrict__ Hbase,
    const float* __restrict__ Wsk,  const float* __restrict__ bskv,
    const float* __restrict__ Wagg, const float* __restrict__ bagg,
    const float* __restrict__ Wout, const float* __restrict__ bout,
    float* __restrict__ out)
{
    __shared__ float sv_lds[64][33];
    __shared__ unsigned short agg_bu[64 * 64];  // [pos][ic] bf16, swizzled
    __shared__ float red_m[64][5];
    __shared__ float red_s[64][5];
    __shared__ float bsum[32];

    int tid  = threadIdx.x;
    int lane = tid & 63;
    int w    = tid >> 6;
    int posG = blockIdx.x * 64;
    int b    = posG >> LOG2N;
    int nb   = posG & (NPOS - 1);

    int lr = lane & 15;
    int lg = lane >> 4;

    if (tid < 32) {
        float s = 0.f;
#pragma unroll 1
        for (int i = 0; i < 19; ++i) s += bskv[i * 32 + tid];
        bsum[tid] = s;
    }

    // ---- stage A': MFMA skip-sum; B-frag = H[i][pos][ic0..ic0+7] (2x float4)
    int posGlob = posG + w * 16 + lr;

    f32x4 dsk0 = {0.f, 0.f, 0.f, 0.f};
    f32x4 dsk1 = {0.f, 0.f, 0.f, 0.f};

#pragma unroll
    for (int kt = 0; kt < 10; ++kt) {
        int i   = kt * 2 + (lg >> 1);
        int ic0 = (lg & 1) * 8;
        short8v bfr = {0, 0, 0, 0, 0, 0, 0, 0};
        short8v af0 = {0, 0, 0, 0, 0, 0, 0, 0};
        short8v af1 = {0, 0, 0, 0, 0, 0, 0, 0};
        if (i < 19) {
            const float4* hb = (const float4*)(Hbase + (size_t)i * HE + (size_t)posGlob * 16 + ic0);
            float4 h0 = hb[0], h1 = hb[1];
            bfr[0] = (short)bf16rne(h0.x); bfr[1] = (short)bf16rne(h0.y);
            bfr[2] = (short)bf16rne(h0.z); bfr[3] = (short)bf16rne(h0.w);
            bfr[4] = (short)bf16rne(h1.x); bfr[5] = (short)bf16rne(h1.y);
            bfr[6] = (short)bf16rne(h1.z); bfr[7] = (short)bf16rne(h1.w);

            const float4* wp0 = (const float4*)(Wsk + (size_t)i * 512 + (0 * 16 + lr) * 16 + ic0);
            const float4* wp1 = (const float4*)(Wsk + (size_t)i * 512 + (1 * 16 + lr) * 16 + ic0);
            float4 a0 = wp0[0], a1 = wp0[1];
            float4 c0v = wp1[0], c1v = wp1[1];
            af0[0] = (short)bf16rne(a0.x); af0[1] = (short)bf16rne(a0.y);
            af0[2] = (short)bf16rne(a0.z); af0[3] = (short)bf16rne(a0.w);
            af0[4] = (short)bf16rne(a1.x); af0[5] = (short)bf16rne(a1.y);
            af0[6] = (short)bf16rne(a1.z); af0[7] = (short)bf16rne(a1.w);
            af1[0] = (short)bf16rne(c0v.x); af1[1] = (short)bf16rne(c0v.y);
            af1[2] = (short)bf16rne(c0v.z); af1[3] = (short)bf16rne(c0v.w);
            af1[4] = (short)bf16rne(c1v.x); af1[5] = (short)bf16rne(c1v.y);
            af1[6] = (short)bf16rne(c1v.z); af1[7] = (short)bf16rne(c1v.w);
        }
        dsk0 = __builtin_amdgcn_mfma_f32_16x16x32_bf16(af0, bfr, dsk0, 0, 0, 0);
        dsk1 = __builtin_amdgcn_mfma_f32_16x16x32_bf16(af1, bfr, dsk1, 0, 0, 0);
    }

    __syncthreads();   // bsum visible

    {
        int posL = w * 16 + lr;
#pragma unroll
        for (int r = 0; r < 4; ++r) {
            int sc0 = 0 * 16 + lg * 4 + r;
            int sc1 = 1 * 16 + lg * 4 + r;
            sv_lds[posL][sc0] = fmaxf(dsk0[r] + bsum[sc0], 0.f);
            sv_lds[posL][sc1] = fmaxf(dsk1[r] + bsum[sc1], 0.f);
        }
    }
    __syncthreads();

    // ---- stage B: agg (VALU, validated)
    {
        float sv[32];
#pragma unroll
        for (int sch = 0; sch < 32; ++sch) sv[sch] = sv_lds[lane][sch];

        float r16[16];
#pragma unroll
        for (int a = 0; a < 16; ++a) {
            int ac = w * 16 + a;
            float acc = bagg[ac];
#pragma unroll
            for (int sch = 0; sch < 32; ++sch)
                acc = fmaf(Wagg[ac * 32 + sch], sv[sch], acc);
            r16[a] = fmaxf(acc, 0.f);
        }
#pragma unroll
        for (int q = 0; q < 8; ++q) {
            unsigned pk = (unsigned)bf16rne(r16[2 * q]) |
                          ((unsigned)bf16rne(r16[2 * q + 1]) << 16);
            int icbyte = (w * 16 + 2 * q) * 2;
            int addr   = lane * 128 + (icbyte ^ ((lane & 7) << 4));
            *(unsigned*)(&agg_bu[addr >> 1]) = pk;
        }
    }
    __syncthreads();

    // ---- stage C: MFMA logits (validated)
    int c0 = w * 64;
    short8v afr[4][2];
#pragma unroll
    for (int ct = 0; ct < 4; ++ct) {
#pragma unroll
        for (int kf = 0; kf < 2; ++kf) {
            int cls = c0 + ct * 16 + lr;
            int k0  = kf * 32 + lg * 8;
            const float4* wp = (const float4*)(Wout + (size_t)cls * 64 + k0);
            float4 w0 = wp[0], w1 = wp[1];
            short8v af;
            af[0] = (short)bf16rne(w0.x); af[1] = (short)bf16rne(w0.y);
            af[2] = (short)bf16rne(w0.z); af[3] = (short)bf16rne(w0.w);
            af[4] = (short)bf16rne(w1.x); af[5] = (short)bf16rne(w1.y);
            af[6] = (short)bf16rne(w1.z); af[7] = (short)bf16rne(w1.w);
            afr[ct][kf] = af;
        }
    }

    f32x4 acc[4][4];
#pragma unroll
    for (int pt = 0; pt < 4; ++pt) {
        int pos = pt * 16 + lr;
        int sw  = (pos & 7) << 4;
        const short8v* bp0 = (const short8v*)(&agg_bu[(pos * 128 + ((0 * 64 + lg * 16) ^ sw)) >> 1]);
        const short8v* bp1 = (const short8v*)(&agg_bu[(pos * 128 + ((1 * 64 + lg * 16) ^ sw)) >> 1]);
        short8v bf0 = *bp0;
        short8v bf1 = *bp1;
#pragma unroll
        for (int ct = 0; ct < 4; ++ct) {
            f32x4 c;
#pragma unroll
            for (int r = 0; r < 4; ++r) c[r] = bout[c0 + ct * 16 + lg * 4 + r];
            c = __builtin_amdgcn_mfma_f32_16x16x32_bf16(afr[ct][0], bf0, c, 0, 0, 0);
            c = __builtin_amdgcn_mfma_f32_16x16x32_bf16(afr[ct][1], bf1, c, 0, 0, 0);
            acc[pt][ct] = c;
        }
    }

#pragma unroll
    for (int pt = 0; pt < 4; ++pt) {
        float m = -1e30f;
#pragma unroll
        for (int ct = 0; ct < 4; ++ct)
#pragma unroll
            for (int r = 0; r < 4; ++r) m = fmaxf(m, acc[pt][ct][r]);
        m = fmaxf(m, __shfl_xor(m, 16));
        m = fmaxf(m, __shfl_xor(m, 32));
        float s = 0.f;
#pragma unroll
        for (int ct = 0; ct < 4; ++ct)
#pragma unroll
            for (int r = 0; r < 4; ++r) s += __expf(acc[pt][ct][r] - m);
        s += __shfl_xor(s, 16);
        s += __shfl_xor(s, 32);
        int pos = pt * 16 + lr;
        red_m[pos][w] = m;
        red_s[pos][w] = s;
    }
    __syncthreads();

#pragma unroll
    for (int pt = 0; pt < 4; ++pt) {
        int pos = pt * 16 + lr;
        float M = fmaxf(fmaxf(red_m[pos][0], red_m[pos][1]),
                        fmaxf(red_m[pos][2], red_m[pos][3]));
        float S = 0.f;
#pragma unroll
        for (int k = 0; k < 4; ++k) S += red_s[pos][k] * __expf(red_m[pos][k] - M);
        float logZ = M + __logf(S);

        int n = nb + pos;
#pragma unroll
        for (int ct = 0; ct < 4; ++ct) {
#pragma unroll
            for (int r = 0; r < 4; ++r) {
                int cls = c0 + ct * 16 + lg * 4 + r;
                out[((size_t)(b * 256 + cls)) * NPOS + n] = acc[pt][ct][r] - logZ;
            }
        }
    }
}

// ======================================================================
// R8 fallback path (channel-major, skip-RMW) — kept verbatim
// ======================================================================
__global__ __launch_bounds__(256) void init_kernel2(
    const int* __restrict__ x_int, const float* __restrict__ W0,
    const float* __restrict__ b0, float* __restrict__ h)
{
    int t0 = (blockIdx.x * 256 + threadIdx.x) * 2;
    int n0 = t0 & (NPOS - 1);
    const float sc = 1.f / 32768.f;
    float xs0  = (n0 >= 1) ? (float)x_int[t0 - 1] * sc : 0.f;
    float xs1  = (float)x_int[t0] * sc;
    float xsp0 = (n0 >= 2) ? (float)x_int[t0 - 2] * sc : 0.f;
    float xsp1 = xs0;
#pragma unroll
    for (int c = 0; c < 16; ++c) {
        float2 o;
        o.x = xs0 + W0[c * 2 + 0] * xsp0 + W0[c * 2 + 1] * xs0 + b0[c];
        o.y = xs1 + W0[c * 2 + 0] * xsp1 + W0[c * 2 + 1] * xs1 + b0[c];
        *(float2*)(h + (size_t)c * TOTAL + t0) = o;
    }
}

__global__ __launch_bounds__(256, 2) void layer_kernel2(
    const float* __restrict__ hIn, float* __restrict__ hOut,
    float* __restrict__ skip,
    const float* __restrict__ wf, const float* __restrict__ bfv,
    const float* __restrict__ wg, const float* __restrict__ bgv,
    const float* __restrict__ wsk, const float* __restrict__ bskv,
    int d, int firstLayer)
{
    int t0 = (blockIdx.x * 256 + threadIdx.x) * 2;
    int n0 = t0 & (NPOS - 1);

    float2 hc[16], hp[16];
#pragma unroll
    for (int ic = 0; ic < 16; ++ic)
        hc[ic] = *(const float2*)(hIn + (size_t)ic * TOTAL + t0);

    if (d == 1) {
        bool v = (n0 >= 1);
        int tm = v ? (t0 - 1) : t0;
#pragma unroll
        for (int ic = 0; ic < 16; ++ic) {
            float x = hIn[(size_t)ic * TOTAL + tm];
            hp[ic].x = v ? x : 0.f;
            hp[ic].y = hc[ic].x;
        }
    } else {
        bool v = (n0 >= d);
        int tm = v ? (t0 - d) : t0;
#pragma unroll
        for (int ic = 0; ic < 16; ++ic) {
            float2 x = *(const float2*)(hIn + (size_t)ic * TOTAL + tm);
            hp[ic].x = v ? x.x : 0.f;
            hp[ic].y = v ? x.y : 0.f;
        }
    }

    float2 fa[16], ga[16];
#pragma unroll
    for (int c = 0; c < 16; ++c) {
        fa[c].x = fa[c].y = bfv[c];
        ga[c].x = ga[c].y = bgv[c];
    }
#pragma unroll
    for (int c = 0; c < 16; ++c) {
#pragma unroll
        for (int ic = 0; ic < 16; ++ic) {
            float wf0 = wf[(c * 16 + ic) * 2 + 0];
            float wf1 = wf[(c * 16 + ic) * 2 + 1];
            float wg0 = wg[(c * 16 + ic) * 2 + 0];
            float wg1 = wg[(c * 16 + ic) * 2 + 1];
            fa[c].x = fmaf(wf0, hp[ic].x, fa[c].x);
            fa[c].x = fmaf(wf1, hc[ic].x, fa[c].x);
            fa[c].y = fmaf(wf0, hp[ic].y, fa[c].y);
            fa[c].y = fmaf(wf1, hc[ic].y, fa[c].y);
            ga[c].x = fmaf(wg0, hp[ic].x, ga[c].x);
            ga[c].x = fmaf(wg1, hc[ic].x, ga[c].x);
            ga[c].y = fmaf(wg0, hp[ic].y, ga[c].y);
            ga[c].y = fmaf(wg1, hc[ic].y, ga[c].y);
        }
    }

#pragma unroll
    for (int c = 0; c < 16; ++c) {
        float2 o;
        o.x = fmaf(fast_tanh(fa[c].x), fast_sigmoid(ga[c].x), hc[c].x);
        o.y = fmaf(fast_tanh(fa[c].y), fast_sigmoid(ga[c].y), hc[c].y);
        *(float2*)(hOut + (size_t)c * TOTAL + t0) = o;
    }

#pragma unroll
    for (int sch = 0; sch < 32; ++sch) {
        float2 acc;
        acc.x = acc.y = bskv[sch];
#pragma unroll
        for (int ic = 0; ic < 16; ++ic) {
            float wv = wsk[sch * 16 + ic];
            acc.x = fmaf(wv, hc[ic].x, acc.x);
            acc.y = fmaf(wv, hc[ic].y, acc.y);
        }
        float* sp = skip + (size_t)sch * TOTAL + t0;
        if (firstLayer) {
            *(float2*)sp = acc;
        } else {
            float2 old = *(const float2*)sp;
            acc.x += old.x; acc.y += old.y;
            *(float2*)sp = acc;
        }
    }
}

__global__ __launch_bounds__(256, 2) void final_kernel(
    const float* __restrict__ skip,
    const float* __restrict__ Wagg, const float* __restrict__ bagg,
    const float* __restrict__ Wout, const float* __restrict__ bout,
    float* __restrict__ out)
{
    __shared__ unsigned short agg_bu[64 * 64];
    __shared__ float red_m[64][5];
    __shared__ float red_s[64][5];

    int tid  = threadIdx.x;
    int lane = tid & 63;
    int w    = tid >> 6;
    int posG = blockIdx.x * 64;
    int b    = posG >> LOG2N;
    int nb   = posG & (NPOS - 1);

    {
        int pos = posG + lane;
        float sv[32];
#pragma unroll
        for (int sch = 0; sch < 32; ++sch)
            sv[sch] = fmaxf(skip[(size_t)sch * TOTAL + pos], 0.f);

        float r16[16];
#pragma unroll
        for (int a = 0; a < 16; ++a) {
            int ac = w * 16 + a;
            float acc = bagg[ac];
#pragma unroll
            for (int sch = 0; sch < 32; ++sch)
                acc = fmaf(Wagg[ac * 32 + sch], sv[sch], acc);
            r16[a] = fmaxf(acc, 0.f);
        }
#pragma unroll
        for (int q = 0; q < 8; ++q) {
            unsigned pk = (unsigned)bf16rne(r16[2 * q]) |
                          ((unsigned)bf16rne(r16[2 * q + 1]) << 16);
            int icbyte = (w * 16 + 2 * q) * 2;
            int addr   = lane * 128 + (icbyte ^ ((lane & 7) << 4));
            *(unsigned*)(&agg_bu[addr >> 1]) = pk;
        }
    }
    __syncthreads();

    int lr = lane & 15;
    int lg = lane >> 4;
    int c0 = w * 64;
    short8v afr[4][2];
#pragma unroll
    for (int ct = 0; ct < 4; ++ct) {
#pragma unroll
        for (int kf = 0; kf < 2; ++kf) {
            int cls = c0 + ct * 16 + lr;
            int k0  = kf * 32 + lg * 8;
            const float4* wp = (const float4*)(Wout + (size_t)cls * 64 + k0);
            float4 w0 = wp[0], w1 = wp[1];
            short8v af;
            af[0] = (short)bf16rne(w0.x); af[1] = (short)bf16rne(w0.y);
            af[2] = (short)bf16rne(w0.z); af[3] = (short)bf16rne(w0.w);
            af[4] = (short)bf16rne(w1.x); af[5] = (short)bf16rne(w1.y);
            af[6] = (short)bf16rne(w1.z); af[7] = (short)bf16rne(w1.w);
            afr[ct][kf] = af;
        }
    }

    f32x4 acc[4][4];
#pragma unroll
    for (int pt = 0; pt < 4; ++pt) {
        int pos = pt * 16 + lr;
        int sw  = (pos & 7) << 4;
        const short8v* bp0 = (const short8v*)(&agg_bu[(pos * 128 + ((0 * 64 + lg * 16) ^ sw)) >> 1]);
        const short8v* bp1 = (const short8v*)(&agg_bu[(pos * 128 + ((1 * 64 + lg * 16) ^ sw)) >> 1]);
        short8v bf0 = *bp0;
        short8v bf1 = *bp1;
#pragma unroll
        for (int ct = 0; ct < 4; ++ct) {
            f32x4 c;
#pragma unroll
            for (int r = 0; r < 4; ++r) c[r] = bout[c0 + ct * 16 + lg * 4 + r];
            c = __builtin_amdgcn_mfma_f32_16x16x32_bf16(afr[ct][0], bf0, c, 0, 0, 0);
            c = __builtin_amdgcn_mfma_f32_16x16x32_bf16(afr[ct][1], bf1, c, 0, 0, 0);
            acc[pt][ct] = c;
        }
    }

#pragma unroll
    for (int pt = 0; pt < 4; ++pt) {
        float m = -1e30f;
#pragma unroll
        for (int ct = 0; ct < 4; ++ct)
#pragma unroll
            for (int r = 0; r < 4; ++r) m = fmaxf(m, acc[pt][ct][r]);
        m = fmaxf(m, __shfl_xor(m, 16));
        m = fmaxf(m, __shfl_xor(m, 32));
        float s = 0.f;
#pragma unroll
        for (int ct = 0; ct < 4; ++ct)
#pragma unroll
            for (int r = 0; r < 4; ++r) s += __expf(acc[pt][ct][r] - m);
        s += __shfl_xor(s, 16);
        s += __shfl_xor(s, 32);
        int pos = pt * 16 + lr;
        red_m[pos][w] = m;
        red_s[pos][w] = s;
    }
    __syncthreads();

#pragma unroll
    for (int pt = 0; pt < 4; ++pt) {
        int pos = pt * 16 + lr;
        float M = fmaxf(fmaxf(red_m[pos][0], red_m[pos][1]),
                        fmaxf(red_m[pos][2], red_m[pos][3]));
        float S = 0.f;
#pragma unroll
        for (int k = 0; k < 4; ++k) S += red_s[pos][k] * __expf(red_m[pos][k] - M);
        float logZ = M + __logf(S);

        int n = nb + pos;
#pragma unroll
        for (int ct = 0; ct < 4; ++ct) {
#pragma unroll
            for (int r = 0; r < 4; ++r) {
                int cls = c0 + ct * 16 + lg * 4 + r;
                out[((size_t)(b * 256 + cls)) * NPOS + n] = acc[pt][ct][r] - logZ;
            }
        }
    }
}

extern "C" void kernel_launch(void* const* d_in, const int* in_sizes, int n_in,
                              void* d_out, int out_size, void* d_ws, size_t ws_size,
                              hipStream_t stream)
{
    const int*   x_int = (const int*)  d_in[0];
    const float* W0    = (const float*)d_in[1];
    const float* b0    = (const float*)d_in[2];
    const float* Wf    = (const float*)d_in[3];
    const float* bfv   = (const float*)d_in[4];
    const float* Wg    = (const float*)d_in[5];
    const float* bgv   = (const float*)d_in[6];
    const float* Wsk   = (const float*)d_in[7];
    const float* bskv  = (const float*)d_in[8];
    const float* Wagg  = (const float*)d_in[9];
    const float* bagg  = (const float*)d_in[10];
    const float* Wout  = (const float*)d_in[11];
    const float* bout  = (const float*)d_in[12];
    float* out = (float*)d_out;

    const int grid2 = TOTAL / (256 * 2);   // 512 blocks, 2 pos/thread

    const size_t needDefer = 19 * HE * sizeof(float);   // 304 MiB

    if (ws_size >= needDefer) {
        // ---------- defer-skip path (row-major H) ----------
        float* Hb = (float*)d_ws;   // H_i at Hb + i*HE, layout [pos][16]

        init_kernel_rm<<<grid2, 256, 0, stream>>>(x_int, W0, b0, Hb);
        for (int i = 0; i < 18; ++i) {   // layer 18's h-update is dead code
            int d = 1 << ((i + 1) % 10);
            layer_kernel_rm<<<grid2, 256, 0, stream>>>(
                Hb + (size_t)i * HE, Hb + (size_t)(i + 1) * HE,
                Wf + (size_t)i * 512, bfv + (size_t)i * 16,
                Wg + (size_t)i * 512, bgv + (size_t)i * 16, d);
        }
        final_kernel_ds3<<<TOTAL / 64, 256, 0, stream>>>(
            Hb, Wsk, bskv, Wagg, bagg, Wout, bout, out);
    } else {
        // ---------- R8 fallback (channel-major) ----------
        const size_t skE = (size_t)32 * TOTAL;
        float* skipb = (float*)d_ws;
        float *hA, *hB;
        if (ws_size >= (skE + 2 * HE) * sizeof(float)) {
            hA = skipb + skE;
            hB = hA + HE;
        } else {
            hA = out + ((size_t)out_size - 2 * HE);
            hB = hA + HE;
        }

        init_kernel2<<<grid2, 256, 0, stream>>>(x_int, W0, b0, hA);
        float* hin = hA;
        float* hout = hB;
        for (int i = 0; i < 19; ++i) {
            int d = 1 << ((i + 1) % 10);
            layer_kernel2<<<grid2, 256, 0, stream>>>(
                hin, hout, skipb,
                Wf + (size_t)i * 512, bfv + (size_t)i * 16,
                Wg + (size_t)i * 512, bgv + (size_t)i * 16,
                Wsk + (size_t)i * 512, bskv + (size_t)i * 32,
                d, (i == 0) ? 1 : 0);
            float* tmp = hin; hin = hout; hout = tmp;
        }
        final_kernel<<<TOTAL / 64, 256, 0, stream>>>(
            skipb, Wagg, bagg, Wout, bout, out);
    }
}